// Round 1
// baseline (554.448 us; speedup 1.0000x reference)
//
#include <hip/hip_runtime.h>
#include <math.h>

#define Bb 8
#define Tt 2048
#define Cc 1024
#define Hh 64
#define TQ 32
#define TK 64
#define SCALE 0.125f

// ---------------- Kernel 1: QKV projection ----------------
// grid: (B*T/32) blocks, 192 threads (3 waves: wave0->Q, wave1->K, wave2->V)
// Each thread: one head-dim column h, 32 rows, full K=1024 dot products.
// x reads are wave-uniform -> scalar loads; W reads lane-coalesced, L2-resident.
__global__ __launch_bounds__(192) void qkv_proj(
    const float* __restrict__ x,
    const float* __restrict__ Wq, const float* __restrict__ Wk,
    const float* __restrict__ Wv,
    float* __restrict__ Qo, float* __restrict__ Ko, float* __restrict__ Vo) {
  const int ROWS = 32;
  int r0 = blockIdx.x * ROWS;
  int t = threadIdx.x;
  int sel = t >> 6;      // 0,1,2 : which projection this wave computes
  int h = t & 63;
  const float* __restrict__ W = (sel == 0) ? Wq : (sel == 1 ? Wk : Wv);
  float* __restrict__ O = (sel == 0) ? Qo : (sel == 1 ? Ko : Vo);

  float acc[ROWS];
#pragma unroll
  for (int r = 0; r < ROWS; ++r) acc[r] = 0.f;

  const float* xb = x + (size_t)r0 * Cc;
  for (int c = 0; c < Cc; c += 4) {
    float w0 = W[(c + 0) * Hh + h];
    float w1 = W[(c + 1) * Hh + h];
    float w2 = W[(c + 2) * Hh + h];
    float w3 = W[(c + 3) * Hh + h];
#pragma unroll
    for (int r = 0; r < ROWS; ++r) {
      float4 xv = *(const float4*)(xb + (size_t)r * Cc + c);
      acc[r] = fmaf(xv.x, w0, acc[r]);
      acc[r] = fmaf(xv.y, w1, acc[r]);
      acc[r] = fmaf(xv.z, w2, acc[r]);
      acc[r] = fmaf(xv.w, w3, acc[r]);
    }
  }
#pragma unroll
  for (int r = 0; r < ROWS; ++r) O[(size_t)(r0 + r) * Hh + h] = acc[r];
}

// ---------------- Kernel 2: causal flash attention ----------------
// grid: B * 32 blocks, 256 threads. Block (b, p) handles query tiles p and
// 63-p (32 queries each) -> uniform 33 key-tile steps per block.
__global__ __launch_bounds__(256) void attn(
    const float* __restrict__ Qg, const float* __restrict__ Kg,
    const float* __restrict__ Vg, float* __restrict__ out) {
  __shared__ __align__(16) float QS[TQ][68];   // pad 68: <=2-way conflicts
  __shared__ __align__(16) float KS[TK][68];
  __shared__ __align__(16) float VS[TK][64];
  __shared__ __align__(16) float SP[TQ][68];
  __shared__ float pm[16][33];   // partial row-max [kgroup][q]
  __shared__ float ps[16][33];   // partial row-sum [kgroup][q]
  __shared__ float mS[TQ], lS[TQ], aS[TQ];

  int b = blockIdx.x >> 5;
  int pair = blockIdx.x & 31;
  int t = threadIdx.x;
  int q2 = t & 15;    // query sub-index: rows q2 and q2+16
  int g = t >> 4;     // 0..15: key-group (S phase) / h-group (PV phase)

  for (int half = 0; half < 2; ++half) {
    int qt = (half == 0) ? pair : (63 - pair);
    int q0 = qt * TQ;

    // stage Q tile
    for (int idx = t; idx < TQ * 16; idx += 256) {
      int row = idx >> 4, col = idx & 15;
      *(float4*)&QS[row][col * 4] =
          *(const float4*)&Qg[((size_t)(b * Tt + q0 + row)) * Hh + col * 4];
    }
    if (t < TQ) { mS[t] = -INFINITY; lS[t] = 0.f; }
    float acc[2][4];
#pragma unroll
    for (int i = 0; i < 2; ++i)
#pragma unroll
      for (int j = 0; j < 4; ++j) acc[i][j] = 0.f;
    __syncthreads();

    int nkt = (q0 + TQ + 63) >> 6;
    for (int kt = 0; kt < nkt; ++kt) {
      // stage K,V tiles (fully coalesced)
      for (int idx = t; idx < TK * 16; idx += 256) {
        int row = idx >> 4, col = idx & 15;
        size_t gofs = ((size_t)(b * Tt + kt * TK + row)) * Hh + col * 4;
        *(float4*)&KS[row][col * 4] = *(const float4*)&Kg[gofs];
        *(float4*)&VS[row][col * 4] = *(const float4*)&Vg[gofs];
      }
      __syncthreads();

      // S = (Q K^T): thread covers rows {q2,q2+16} x keys {4g..4g+3}
      float s0[4], s1[4];
#pragma unroll
      for (int kk = 0; kk < 4; ++kk) { s0[kk] = 0.f; s1[kk] = 0.f; }
      for (int c4 = 0; c4 < 16; ++c4) {
        float4 qa = *(const float4*)&QS[q2][c4 * 4];
        float4 qb = *(const float4*)&QS[q2 + 16][c4 * 4];
#pragma unroll
        for (int kk = 0; kk < 4; ++kk) {
          float4 kv = *(const float4*)&KS[g * 4 + kk][c4 * 4];
          s0[kk] = fmaf(qa.x, kv.x, s0[kk]);
          s0[kk] = fmaf(qa.y, kv.y, s0[kk]);
          s0[kk] = fmaf(qa.z, kv.z, s0[kk]);
          s0[kk] = fmaf(qa.w, kv.w, s0[kk]);
          s1[kk] = fmaf(qb.x, kv.x, s1[kk]);
          s1[kk] = fmaf(qb.y, kv.y, s1[kk]);
          s1[kk] = fmaf(qb.z, kv.z, s1[kk]);
          s1[kk] = fmaf(qb.w, kv.w, s1[kk]);
        }
      }
      // scale + causal mask + partial max
      float lm0 = -INFINITY, lm1 = -INFINITY;
#pragma unroll
      for (int kk = 0; kk < 4; ++kk) {
        int kglob = kt * TK + g * 4 + kk;
        s0[kk] = (kglob <= q0 + q2) ? s0[kk] * SCALE : -INFINITY;
        s1[kk] = (kglob <= q0 + q2 + 16) ? s1[kk] * SCALE : -INFINITY;
        lm0 = fmaxf(lm0, s0[kk]);
        lm1 = fmaxf(lm1, s1[kk]);
      }
      pm[g][q2] = lm0;
      pm[g][q2 + 16] = lm1;
      __syncthreads();

      // per-row new max + alpha
      if (t < TQ) {
        float m_old = mS[t];
        float nm = m_old;
#pragma unroll
        for (int j = 0; j < 16; ++j) nm = fmaxf(nm, pm[j][t]);
        mS[t] = nm;
        aS[t] = __expf(m_old - nm);
      }
      __syncthreads();

      // exponentiate in registers, write P + partial sums
      float nm0 = mS[q2], nm1 = mS[q2 + 16];
      float sum0 = 0.f, sum1 = 0.f;
#pragma unroll
      for (int kk = 0; kk < 4; ++kk) {
        s0[kk] = __expf(s0[kk] - nm0); sum0 += s0[kk];
        s1[kk] = __expf(s1[kk] - nm1); sum1 += s1[kk];
      }
      *(float4*)&SP[q2][g * 4] = make_float4(s0[0], s0[1], s0[2], s0[3]);
      *(float4*)&SP[q2 + 16][g * 4] = make_float4(s1[0], s1[1], s1[2], s1[3]);
      ps[g][q2] = sum0;
      ps[g][q2 + 16] = sum1;
      __syncthreads();

      // l update (first 32 threads) + PV accumulate (all threads)
      if (t < TQ) {
        float sum = 0.f;
#pragma unroll
        for (int j = 0; j < 16; ++j) sum += ps[j][t];
        lS[t] = lS[t] * aS[t] + sum;
      }
      float al0 = aS[q2], al1 = aS[q2 + 16];
#pragma unroll
      for (int j = 0; j < 4; ++j) { acc[0][j] *= al0; acc[1][j] *= al1; }
      for (int k4 = 0; k4 < 16; ++k4) {
        float4 p0 = *(const float4*)&SP[q2][k4 * 4];
        float4 p1 = *(const float4*)&SP[q2 + 16][k4 * 4];
        float pa[4] = {p0.x, p0.y, p0.z, p0.w};
        float pb[4] = {p1.x, p1.y, p1.z, p1.w};
#pragma unroll
        for (int kk = 0; kk < 4; ++kk) {
          float4 vv = *(const float4*)&VS[k4 * 4 + kk][g * 4];
          acc[0][0] = fmaf(pa[kk], vv.x, acc[0][0]);
          acc[0][1] = fmaf(pa[kk], vv.y, acc[0][1]);
          acc[0][2] = fmaf(pa[kk], vv.z, acc[0][2]);
          acc[0][3] = fmaf(pa[kk], vv.w, acc[0][3]);
          acc[1][0] = fmaf(pb[kk], vv.x, acc[1][0]);
          acc[1][1] = fmaf(pb[kk], vv.y, acc[1][1]);
          acc[1][2] = fmaf(pb[kk], vv.z, acc[1][2]);
          acc[1][3] = fmaf(pb[kk], vv.w, acc[1][3]);
        }
      }
      __syncthreads();
    }

    // epilogue: normalize and store (h-range = g*4..g*4+3)
    float inv0 = 1.f / lS[q2];
    float inv1 = 1.f / lS[q2 + 16];
    float4 o0 = make_float4(acc[0][0] * inv0, acc[0][1] * inv0,
                            acc[0][2] * inv0, acc[0][3] * inv0);
    float4 o1 = make_float4(acc[1][0] * inv1, acc[1][1] * inv1,
                            acc[1][2] * inv1, acc[1][3] * inv1);
    *(float4*)&out[((size_t)(b * Tt + q0 + q2)) * Hh + g * 4] = o0;
    *(float4*)&out[((size_t)(b * Tt + q0 + q2 + 16)) * Hh + g * 4] = o1;
    __syncthreads();  // before next half re-stages LDS
  }
}

extern "C" void kernel_launch(void* const* d_in, const int* in_sizes, int n_in,
                              void* d_out, int out_size, void* d_ws, size_t ws_size,
                              hipStream_t stream) {
  const float* x = (const float*)d_in[0];
  const float* Wq = (const float*)d_in[1];
  const float* Wk = (const float*)d_in[2];
  const float* Wv = (const float*)d_in[3];
  float* out = (float*)d_out;

  // workspace: Q,K,V scratch, 4 MB each
  const size_t BTH = (size_t)Bb * Tt * Hh;  // 1,048,576
  float* Qs = (float*)d_ws;
  float* Ks = Qs + BTH;
  float* Vs = Ks + BTH;

  dim3 g1(Bb * Tt / 32), b1(192);
  qkv_proj<<<g1, b1, 0, stream>>>(x, Wq, Wk, Wv, Qs, Ks, Vs);

  dim3 g2(Bb * 32), b2(256);
  attn<<<g2, b2, 0, stream>>>(Qs, Ks, Vs, out);
}

// Round 2
// 266.884 us; speedup vs baseline: 2.0775x; 2.0775x over previous
//
#include <hip/hip_runtime.h>
#include <math.h>

#define Bb 8
#define Tt 2048
#define Cc 1024
#define Hh 64
#define TQ 32
#define TK 64
#define SCALE 0.125f

typedef __attribute__((ext_vector_type(8))) short short8;
typedef __attribute__((ext_vector_type(4))) float floatx4;

__device__ inline unsigned short f2bf(float f) {
  unsigned int u = __builtin_bit_cast(unsigned int, f);
  u += 0x7fff + ((u >> 16) & 1);   // RNE round to bf16
  return (unsigned short)(u >> 16);
}

// ---------------- Kernel 1: QKV projection via bf16 MFMA ----------------
// grid: 256 M-tiles * 3 (Q,K,V) = 768 blocks, 256 threads (4 waves).
// Block computes a 64x64 output tile: wave w covers rows w*16..w*16+15,
// all 64 cols (4 MFMA 16x16 subtiles), K staged 32 per step (one MFMA K).
// LDS rows padded to 40 ushorts (80B stride -> <=2-way bank conflict, free).
__global__ __launch_bounds__(256) void qkv_mfma(
    const float* __restrict__ x,
    const float* __restrict__ Wq, const float* __restrict__ Wk,
    const float* __restrict__ Wv,
    float* __restrict__ Qo, float* __restrict__ Ko, float* __restrict__ Vo) {
  __shared__ unsigned short As[64][40];  // A tile: [row][k] bf16
  __shared__ unsigned short Bs[64][40];  // B^T tile: [h][k] bf16

  int bid = blockIdx.x;
  int mt = bid / 3;
  int wsel = bid % 3;
  const float* __restrict__ W = (wsel == 0) ? Wq : (wsel == 1 ? Wk : Wv);
  float* __restrict__ O = (wsel == 0) ? Qo : (wsel == 1 ? Ko : Vo);

  int t = threadIdx.x;
  int wave = t >> 6, lane = t & 63;
  int lrow = lane & 15, quad = lane >> 4;

  floatx4 acc[4];
#pragma unroll
  for (int sn = 0; sn < 4; ++sn)
#pragma unroll
    for (int r = 0; r < 4; ++r) acc[sn][r] = 0.f;

  const float* xb = x + (size_t)mt * 64 * Cc;

  for (int kk = 0; kk < 32; ++kk) {
    __syncthreads();  // previous compute done before overwriting LDS
    // stage A: 64 rows x 32 k of x, fp32 -> bf16. 512 float4 tasks, 2/thread
#pragma unroll
    for (int i = 0; i < 2; ++i) {
      int task = t + i * 256;
      int row = task >> 3;      // 0..63
      int cg = task & 7;        // k group of 4
      float4 v = *(const float4*)(xb + (size_t)row * Cc + kk * 32 + cg * 4);
      ushort4 p = make_ushort4(f2bf(v.x), f2bf(v.y), f2bf(v.z), f2bf(v.w));
      *(ushort4*)&As[row][cg * 4] = p;
    }
    // stage B^T: Bs[h][c] = W[kk*32+c][h]. 512 tasks of 4 k each, 2/thread
#pragma unroll
    for (int i = 0; i < 2; ++i) {
      int task = t + i * 256;
      int h = task & 63;
      int cg = task >> 6;       // 0..7
      int c0 = kk * 32 + cg * 4;
      ushort4 p = make_ushort4(f2bf(W[(size_t)(c0 + 0) * Hh + h]),
                               f2bf(W[(size_t)(c0 + 1) * Hh + h]),
                               f2bf(W[(size_t)(c0 + 2) * Hh + h]),
                               f2bf(W[(size_t)(c0 + 3) * Hh + h]));
      *(ushort4*)&Bs[h][cg * 4] = p;
    }
    __syncthreads();
    // compute: a-frag = A[m=lane&15][k=quad*8+j]; b-frag = B[k=quad*8+j][n=lane&15]
    short8 a = *(const short8*)&As[wave * 16 + lrow][quad * 8];
#pragma unroll
    for (int sn = 0; sn < 4; ++sn) {
      short8 b = *(const short8*)&Bs[sn * 16 + lrow][quad * 8];
      acc[sn] = __builtin_amdgcn_mfma_f32_16x16x32_bf16(a, b, acc[sn], 0, 0, 0);
    }
  }
  // epilogue: D row = quad*4 + reg, col = lane&15
  int row0 = mt * 64 + wave * 16 + quad * 4;
#pragma unroll
  for (int sn = 0; sn < 4; ++sn) {
    int col = sn * 16 + lrow;
#pragma unroll
    for (int r = 0; r < 4; ++r) {
      O[(size_t)(row0 + r) * Hh + col] = acc[sn][r];
    }
  }
}

// ---------------- Kernel 2: causal flash attention (unchanged) ----------------
__global__ __launch_bounds__(256) void attn(
    const float* __restrict__ Qg, const float* __restrict__ Kg,
    const float* __restrict__ Vg, float* __restrict__ out) {
  __shared__ __align__(16) float QS[TQ][68];
  __shared__ __align__(16) float KS[TK][68];
  __shared__ __align__(16) float VS[TK][64];
  __shared__ __align__(16) float SP[TQ][68];
  __shared__ float pm[16][33];
  __shared__ float ps[16][33];
  __shared__ float mS[TQ], lS[TQ], aS[TQ];

  int b = blockIdx.x >> 5;
  int pair = blockIdx.x & 31;
  int t = threadIdx.x;
  int q2 = t & 15;
  int g = t >> 4;

  for (int half = 0; half < 2; ++half) {
    int qt = (half == 0) ? pair : (63 - pair);
    int q0 = qt * TQ;

    for (int idx = t; idx < TQ * 16; idx += 256) {
      int row = idx >> 4, col = idx & 15;
      *(float4*)&QS[row][col * 4] =
          *(const float4*)&Qg[((size_t)(b * Tt + q0 + row)) * Hh + col * 4];
    }
    if (t < TQ) { mS[t] = -INFINITY; lS[t] = 0.f; }
    float acc[2][4];
#pragma unroll
    for (int i = 0; i < 2; ++i)
#pragma unroll
      for (int j = 0; j < 4; ++j) acc[i][j] = 0.f;
    __syncthreads();

    int nkt = (q0 + TQ + 63) >> 6;
    for (int kt = 0; kt < nkt; ++kt) {
      for (int idx = t; idx < TK * 16; idx += 256) {
        int row = idx >> 4, col = idx & 15;
        size_t gofs = ((size_t)(b * Tt + kt * TK + row)) * Hh + col * 4;
        *(float4*)&KS[row][col * 4] = *(const float4*)&Kg[gofs];
        *(float4*)&VS[row][col * 4] = *(const float4*)&Vg[gofs];
      }
      __syncthreads();

      float s0[4], s1[4];
#pragma unroll
      for (int kk = 0; kk < 4; ++kk) { s0[kk] = 0.f; s1[kk] = 0.f; }
      for (int c4 = 0; c4 < 16; ++c4) {
        float4 qa = *(const float4*)&QS[q2][c4 * 4];
        float4 qb = *(const float4*)&QS[q2 + 16][c4 * 4];
#pragma unroll
        for (int kk = 0; kk < 4; ++kk) {
          float4 kv = *(const float4*)&KS[g * 4 + kk][c4 * 4];
          s0[kk] = fmaf(qa.x, kv.x, s0[kk]);
          s0[kk] = fmaf(qa.y, kv.y, s0[kk]);
          s0[kk] = fmaf(qa.z, kv.z, s0[kk]);
          s0[kk] = fmaf(qa.w, kv.w, s0[kk]);
          s1[kk] = fmaf(qb.x, kv.x, s1[kk]);
          s1[kk] = fmaf(qb.y, kv.y, s1[kk]);
          s1[kk] = fmaf(qb.z, kv.z, s1[kk]);
          s1[kk] = fmaf(qb.w, kv.w, s1[kk]);
        }
      }
      float lm0 = -INFINITY, lm1 = -INFINITY;
#pragma unroll
      for (int kk = 0; kk < 4; ++kk) {
        int kglob = kt * TK + g * 4 + kk;
        s0[kk] = (kglob <= q0 + q2) ? s0[kk] * SCALE : -INFINITY;
        s1[kk] = (kglob <= q0 + q2 + 16) ? s1[kk] * SCALE : -INFINITY;
        lm0 = fmaxf(lm0, s0[kk]);
        lm1 = fmaxf(lm1, s1[kk]);
      }
      pm[g][q2] = lm0;
      pm[g][q2 + 16] = lm1;
      __syncthreads();

      if (t < TQ) {
        float m_old = mS[t];
        float nm = m_old;
#pragma unroll
        for (int j = 0; j < 16; ++j) nm = fmaxf(nm, pm[j][t]);
        mS[t] = nm;
        aS[t] = __expf(m_old - nm);
      }
      __syncthreads();

      float nm0 = mS[q2], nm1 = mS[q2 + 16];
      float sum0 = 0.f, sum1 = 0.f;
#pragma unroll
      for (int kk = 0; kk < 4; ++kk) {
        s0[kk] = __expf(s0[kk] - nm0); sum0 += s0[kk];
        s1[kk] = __expf(s1[kk] - nm1); sum1 += s1[kk];
      }
      *(float4*)&SP[q2][g * 4] = make_float4(s0[0], s0[1], s0[2], s0[3]);
      *(float4*)&SP[q2 + 16][g * 4] = make_float4(s1[0], s1[1], s1[2], s1[3]);
      ps[g][q2] = sum0;
      ps[g][q2 + 16] = sum1;
      __syncthreads();

      if (t < TQ) {
        float sum = 0.f;
#pragma unroll
        for (int j = 0; j < 16; ++j) sum += ps[j][t];
        lS[t] = lS[t] * aS[t] + sum;
      }
      float al0 = aS[q2], al1 = aS[q2 + 16];
#pragma unroll
      for (int j = 0; j < 4; ++j) { acc[0][j] *= al0; acc[1][j] *= al1; }
      for (int k4 = 0; k4 < 16; ++k4) {
        float4 p0 = *(const float4*)&SP[q2][k4 * 4];
        float4 p1 = *(const float4*)&SP[q2 + 16][k4 * 4];
        float pa[4] = {p0.x, p0.y, p0.z, p0.w};
        float pb[4] = {p1.x, p1.y, p1.z, p1.w};
#pragma unroll
        for (int kk = 0; kk < 4; ++kk) {
          float4 vv = *(const float4*)&VS[k4 * 4 + kk][g * 4];
          acc[0][0] = fmaf(pa[kk], vv.x, acc[0][0]);
          acc[0][1] = fmaf(pa[kk], vv.y, acc[0][1]);
          acc[0][2] = fmaf(pa[kk], vv.z, acc[0][2]);
          acc[0][3] = fmaf(pa[kk], vv.w, acc[0][3]);
          acc[1][0] = fmaf(pb[kk], vv.x, acc[1][0]);
          acc[1][1] = fmaf(pb[kk], vv.y, acc[1][1]);
          acc[1][2] = fmaf(pb[kk], vv.z, acc[1][2]);
          acc[1][3] = fmaf(pb[kk], vv.w, acc[1][3]);
        }
      }
      __syncthreads();
    }

    float inv0 = 1.f / lS[q2];
    float inv1 = 1.f / lS[q2 + 16];
    float4 o0 = make_float4(acc[0][0] * inv0, acc[0][1] * inv0,
                            acc[0][2] * inv0, acc[0][3] * inv0);
    float4 o1 = make_float4(acc[1][0] * inv1, acc[1][1] * inv1,
                            acc[1][2] * inv1, acc[1][3] * inv1);
    *(float4*)&out[((size_t)(b * Tt + q0 + q2)) * Hh + g * 4] = o0;
    *(float4*)&out[((size_t)(b * Tt + q0 + q2 + 16)) * Hh + g * 4] = o1;
    __syncthreads();
  }
}

extern "C" void kernel_launch(void* const* d_in, const int* in_sizes, int n_in,
                              void* d_out, int out_size, void* d_ws, size_t ws_size,
                              hipStream_t stream) {
  const float* x = (const float*)d_in[0];
  const float* Wq = (const float*)d_in[1];
  const float* Wk = (const float*)d_in[2];
  const float* Wv = (const float*)d_in[3];
  float* out = (float*)d_out;

  const size_t BTH = (size_t)Bb * Tt * Hh;
  float* Qs = (float*)d_ws;
  float* Ks = Qs + BTH;
  float* Vs = Ks + BTH;

  dim3 g1(256 * 3), b1(256);
  qkv_mfma<<<g1, b1, 0, stream>>>(x, Wq, Wk, Wv, Qs, Ks, Vs);

  dim3 g2(Bb * 32), b2(256);
  attn<<<g2, b2, 0, stream>>>(Qs, Ks, Vs, out);
}

// Round 3
// 182.952 us; speedup vs baseline: 3.0306x; 1.4588x over previous
//
#include <hip/hip_runtime.h>
#include <math.h>

#define Bb 8
#define Tt 2048
#define Cc 1024
#define Hh 64
#define SCALE 0.125f
#define BT (Bb * Tt)          // 16384 tokens

typedef __attribute__((ext_vector_type(8))) short short8;
typedef __attribute__((ext_vector_type(4))) float floatx4;

__device__ inline unsigned short f2bf(float f) {
  unsigned int u = __builtin_bit_cast(unsigned int, f);
  u += 0x7fff + ((u >> 16) & 1);   // RNE
  return (unsigned short)(u >> 16);
}

// ---------- Kernel 0: W fp32 [C][H] -> WT bf16 [192][C] (transposed) ----------
__global__ __launch_bounds__(256) void wconv(
    const float* __restrict__ Wq, const float* __restrict__ Wk,
    const float* __restrict__ Wv, unsigned short* __restrict__ WT) {
  __shared__ __align__(16) float Ttile[32][68];
  int bid = blockIdx.x;
  int w = bid >> 5;             // which W
  int c0 = (bid & 31) * 32;     // c-range
  const float* __restrict__ W = (w == 0) ? Wq : (w == 1 ? Wk : Wv);
  int t = threadIdx.x;
  {
    int i = t >> 3, h0 = (t & 7) * 8;
    float4 a = *(const float4*)&W[(size_t)(c0 + i) * Hh + h0];
    float4 b = *(const float4*)&W[(size_t)(c0 + i) * Hh + h0 + 4];
    *(float4*)&Ttile[i][h0] = a;
    *(float4*)&Ttile[i][h0 + 4] = b;
  }
  __syncthreads();
  int h = t >> 2, jj = t & 3;
  unsigned short tmp[8];
#pragma unroll
  for (int ii = 0; ii < 8; ++ii) tmp[ii] = f2bf(Ttile[jj * 8 + ii][h]);
  unsigned short* dst = &WT[(size_t)(w * 64 + h) * Cc + c0 + jj * 8];
  *(ushort4*)dst = make_ushort4(tmp[0], tmp[1], tmp[2], tmp[3]);
  *(ushort4*)(dst + 4) = make_ushort4(tmp[4], tmp[5], tmp[6], tmp[7]);
}

// ---------- Kernel 1: fused QKV projection, bf16 outputs ----------
// grid 256 blocks (M=64 rows each), 256 threads. N=192 (Q|K|V), BK=32.
// Outputs: Qb[t][h], Kb[t][h] bf16 row-major; VTb[h][t] bf16 transposed.
__global__ __launch_bounds__(256) void qkv2(
    const float* __restrict__ x, const unsigned short* __restrict__ WT,
    unsigned short* __restrict__ Qb, unsigned short* __restrict__ Kb,
    unsigned short* __restrict__ VTb) {
  __shared__ __align__(16) unsigned short As[64][32];
  __shared__ __align__(16) unsigned short Bs[192][32];

  int mt = blockIdx.x;
  int t = threadIdx.x;
  int wv = t >> 6, lane = t & 63;
  int lrow = lane & 15, quad = lane >> 4;

  floatx4 acc[12];
#pragma unroll
  for (int sn = 0; sn < 12; ++sn)
#pragma unroll
    for (int r = 0; r < 4; ++r) acc[sn][r] = 0.f;

  const float* xb = x + (size_t)mt * 64 * Cc;
  int arow = t >> 2, akc = t & 3;

  for (int kk = 0; kk < 32; ++kk) {
    int k0 = kk * 32;
    __syncthreads();  // prior MFMAs done before overwrite
    // stage A (fp32 -> bf16): 64 rows x 32 k
    {
      const float* src = xb + (size_t)arow * Cc + k0 + akc * 8;
      float4 v0 = *(const float4*)src;
      float4 v1 = *(const float4*)(src + 4);
      *(ushort4*)&As[arow][akc * 8] =
          make_ushort4(f2bf(v0.x), f2bf(v0.y), f2bf(v0.z), f2bf(v0.w));
      *(ushort4*)&As[arow][akc * 8 + 4] =
          make_ushort4(f2bf(v1.x), f2bf(v1.y), f2bf(v1.z), f2bf(v1.w));
    }
    // stage B (bf16 copy): 192 rows x 32 k
#pragma unroll
    for (int i = 0; i < 3; ++i) {
      int task = t + i * 256;
      int row = task >> 2, kc = task & 3;
      *(uint4*)&Bs[row][kc * 8] =
          *(const uint4*)&WT[(size_t)row * Cc + k0 + kc * 8];
    }
    __syncthreads();
    short8 a = *(const short8*)&As[wv * 16 + lrow][quad * 8];
#pragma unroll
    for (int sn = 0; sn < 12; ++sn) {
      short8 b = *(const short8*)&Bs[sn * 16 + lrow][quad * 8];
      acc[sn] = __builtin_amdgcn_mfma_f32_16x16x32_bf16(a, b, acc[sn], 0, 0, 0);
    }
  }

  // V: direct packed stores to VTb[h][token] (4 consecutive tokens per lane)
#pragma unroll
  for (int s2 = 0; s2 < 4; ++s2) {
    int sn = 8 + s2;
    int h = s2 * 16 + lrow;
    int tok = mt * 64 + wv * 16 + quad * 4;
    *(ushort4*)&VTb[(size_t)h * BT + tok] =
        make_ushort4(f2bf(acc[sn][0]), f2bf(acc[sn][1]),
                     f2bf(acc[sn][2]), f2bf(acc[sn][3]));
  }
  // Q, K: assemble 64x64 bf16 tile in LDS, then coalesced 16B stores
  unsigned short(*Ot)[72] = (unsigned short(*)[72]) & Bs[0][0];  // 9216 B <= Bs
#pragma unroll
  for (int part = 0; part < 2; ++part) {
    __syncthreads();
#pragma unroll
    for (int s2 = 0; s2 < 4; ++s2) {
      int sn = part * 4 + s2;
      int col = s2 * 16 + lrow;
#pragma unroll
      for (int r = 0; r < 4; ++r) Ot[wv * 16 + quad * 4 + r][col] = f2bf(acc[sn][r]);
    }
    __syncthreads();
    unsigned short* dst = part ? Kb : Qb;
#pragma unroll
    for (int i = 0; i < 2; ++i) {
      int task = t + i * 256;
      int row = task >> 3, c = task & 7;
      *(uint4*)&dst[(size_t)(mt * 64 + row) * Hh + c * 8] =
          *(const uint4*)&Ot[row][c * 8];
    }
  }
}

// ---------- Kernel 2: causal flash attention, bf16 MFMA ----------
// grid 512 blocks: half 0 -> qt = j (0..31), half 1 -> qt = 63-j, so the two
// blocks co-resident on a CU have complementary causal work. 256 threads.
// Wave wv: rows (wv&1)*16, key/h cols (wv>>1)*32. Pairs (wv, wv^2) share rows.
__global__ __launch_bounds__(256, 2) void attn2(
    const unsigned short* __restrict__ Qb, const unsigned short* __restrict__ Kb,
    const unsigned short* __restrict__ VTb, float* __restrict__ out) {
  __shared__ __align__(16) unsigned short Qs[32][72];
  __shared__ __align__(16) unsigned short Ks[64][72];
  __shared__ __align__(16) unsigned short VTs[64][72];
  __shared__ __align__(16) unsigned short Ps[32][72];
  __shared__ float pmax[4][16];
  __shared__ float psum[4][16];

  int bid = blockIdx.x;
  int half = bid >> 8;
  int pid = bid & 255;
  int b = pid >> 5;
  int j = pid & 31;
  int qt = half == 0 ? j : (63 - j);
  int q0 = qt * 32;

  int t = threadIdx.x;
  int wv = t >> 6, lane = t & 63;
  int lrow = lane & 15, quad = lane >> 4;
  int mrow = (wv & 1) * 16;    // S/P/O row group
  int ncol = (wv >> 1) * 32;   // key group (S) / h group (PV)

  // stage Q tile (32 x 64 bf16)
  {
    int row = t >> 3, hc = t & 7;
    *(uint4*)&Qs[row][hc * 8] =
        *(const uint4*)&Qb[(size_t)(b * Tt + q0 + row) * Hh + hc * 8];
  }
  float m_r[4], l_r[4];
  floatx4 acc_o[2];
#pragma unroll
  for (int r = 0; r < 4; ++r) { m_r[r] = -INFINITY; l_r[r] = 0.f; }
#pragma unroll
  for (int sn = 0; sn < 2; ++sn)
#pragma unroll
    for (int r = 0; r < 4; ++r) acc_o[sn][r] = 0.f;
  __syncthreads();

  short8 aq0 = *(const short8*)&Qs[mrow + lrow][quad * 8];
  short8 aq1 = *(const short8*)&Qs[mrow + lrow][32 + quad * 8];

  int nkt = (q0 + 32 + 63) >> 6;
  for (int kt = 0; kt < nkt; ++kt) {
    // stage K [key][h] and VT [h][key] tiles (64x64 bf16 each)
#pragma unroll
    for (int i = 0; i < 2; ++i) {
      int task = t + i * 256;
      int row = task >> 3, cc = task & 7;
      *(uint4*)&Ks[row][cc * 8] =
          *(const uint4*)&Kb[(size_t)(b * Tt + kt * 64 + row) * Hh + cc * 8];
      *(uint4*)&VTs[row][cc * 8] =
          *(const uint4*)&VTb[(size_t)row * BT + b * Tt + kt * 64 + cc * 8];
    }
    __syncthreads();

    // S = Q K^T for this wave's 16 rows x 32 keys
    floatx4 acc_s[2];
#pragma unroll
    for (int sn = 0; sn < 2; ++sn) {
#pragma unroll
      for (int r = 0; r < 4; ++r) acc_s[sn][r] = 0.f;
      short8 b0 = *(const short8*)&Ks[ncol + sn * 16 + lrow][quad * 8];
      acc_s[sn] = __builtin_amdgcn_mfma_f32_16x16x32_bf16(aq0, b0, acc_s[sn], 0, 0, 0);
      short8 b1 = *(const short8*)&Ks[ncol + sn * 16 + lrow][32 + quad * 8];
      acc_s[sn] = __builtin_amdgcn_mfma_f32_16x16x32_bf16(aq1, b1, acc_s[sn], 0, 0, 0);
    }
    // scale + causal mask
    float sm[2][4];
#pragma unroll
    for (int sn = 0; sn < 2; ++sn) {
      int kglob = kt * 64 + ncol + sn * 16 + lrow;
#pragma unroll
      for (int r = 0; r < 4; ++r) {
        int qglob = q0 + mrow + quad * 4 + r;
        sm[sn][r] = (kglob <= qglob) ? acc_s[sn][r] * SCALE : -INFINITY;
      }
    }
    // row max over this wave's 32 keys (shfl over 16 lanes)
    float tmax[4];
#pragma unroll
    for (int r = 0; r < 4; ++r) {
      float v = fmaxf(sm[0][r], sm[1][r]);
      v = fmaxf(v, __shfl_xor(v, 1));
      v = fmaxf(v, __shfl_xor(v, 2));
      v = fmaxf(v, __shfl_xor(v, 4));
      v = fmaxf(v, __shfl_xor(v, 8));
      tmax[r] = v;
    }
    if (lrow == 0) {
#pragma unroll
      for (int r = 0; r < 4; ++r) pmax[wv][quad * 4 + r] = tmax[r];
    }
    __syncthreads();

    float mnew[4], alpha[4];
#pragma unroll
    for (int r = 0; r < 4; ++r) {
      int ri = quad * 4 + r;
      mnew[r] = fmaxf(m_r[r], fmaxf(pmax[wv][ri], pmax[wv ^ 2][ri]));
      alpha[r] = __expf(m_r[r] - mnew[r]);
      m_r[r] = mnew[r];
    }
    // exp + partial sums + write P (bf16) to LDS
    float p[2][4];
    float tsum[4];
#pragma unroll
    for (int r = 0; r < 4; ++r) {
      p[0][r] = __expf(sm[0][r] - mnew[r]);
      p[1][r] = __expf(sm[1][r] - mnew[r]);
      float v = p[0][r] + p[1][r];
      v += __shfl_xor(v, 1);
      v += __shfl_xor(v, 2);
      v += __shfl_xor(v, 4);
      v += __shfl_xor(v, 8);
      tsum[r] = v;
    }
    if (lrow == 0) {
#pragma unroll
      for (int r = 0; r < 4; ++r) psum[wv][quad * 4 + r] = tsum[r];
    }
#pragma unroll
    for (int sn = 0; sn < 2; ++sn)
#pragma unroll
      for (int r = 0; r < 4; ++r)
        Ps[mrow + quad * 4 + r][ncol + sn * 16 + lrow] = f2bf(p[sn][r]);
    __syncthreads();

    // l update + O rescale
#pragma unroll
    for (int r = 0; r < 4; ++r) {
      int ri = quad * 4 + r;
      l_r[r] = l_r[r] * alpha[r] + psum[wv][ri] + psum[wv ^ 2][ri];
      acc_o[0][r] *= alpha[r];
      acc_o[1][r] *= alpha[r];
    }
    // PV: O += P * V  (A = Ps rows, B = VTs rows)
    short8 ap0 = *(const short8*)&Ps[mrow + lrow][quad * 8];
    short8 ap1 = *(const short8*)&Ps[mrow + lrow][32 + quad * 8];
#pragma unroll
    for (int sn = 0; sn < 2; ++sn) {
      short8 b0 = *(const short8*)&VTs[ncol + sn * 16 + lrow][quad * 8];
      acc_o[sn] = __builtin_amdgcn_mfma_f32_16x16x32_bf16(ap0, b0, acc_o[sn], 0, 0, 0);
      short8 b1 = *(const short8*)&VTs[ncol + sn * 16 + lrow][32 + quad * 8];
      acc_o[sn] = __builtin_amdgcn_mfma_f32_16x16x32_bf16(ap1, b1, acc_o[sn], 0, 0, 0);
    }
    __syncthreads();  // PV reads done before next staging
  }

  // epilogue: normalize, fp32 store
#pragma unroll
  for (int sn = 0; sn < 2; ++sn) {
    int col = ncol + sn * 16 + lrow;
#pragma unroll
    for (int r = 0; r < 4; ++r) {
      int row = q0 + mrow + quad * 4 + r;
      out[(size_t)(b * Tt + row) * Hh + col] = acc_o[sn][r] / l_r[r];
    }
  }
}

extern "C" void kernel_launch(void* const* d_in, const int* in_sizes, int n_in,
                              void* d_out, int out_size, void* d_ws, size_t ws_size,
                              hipStream_t stream) {
  const float* x = (const float*)d_in[0];
  const float* Wq = (const float*)d_in[1];
  const float* Wk = (const float*)d_in[2];
  const float* Wv = (const float*)d_in[3];
  float* out = (float*)d_out;

  unsigned short* WT = (unsigned short*)d_ws;          // [192][1024]
  unsigned short* Qb = WT + 192 * 1024;                // [BT][64]
  unsigned short* Kb = Qb + (size_t)BT * Hh;           // [BT][64]
  unsigned short* VTb = Kb + (size_t)BT * Hh;          // [64][BT]

  wconv<<<dim3(96), dim3(256), 0, stream>>>(Wq, Wk, Wv, WT);
  qkv2<<<dim3(256), dim3(256), 0, stream>>>(x, WT, Qb, Kb, VTb);
  attn2<<<dim3(512), dim3(256), 0, stream>>>(Qb, Kb, VTb, out);
}

// Round 4
// 149.648 us; speedup vs baseline: 3.7050x; 1.2225x over previous
//
#include <hip/hip_runtime.h>
#include <math.h>

#define Bb 8
#define Tt 2048
#define Cc 1024
#define Hh 64
#define BT (Bb * Tt)          // 16384 tokens
#define SLOG2E 0.18033688011112042f   // 0.125 * log2(e)

typedef __attribute__((ext_vector_type(8))) short short8;
typedef __attribute__((ext_vector_type(4))) float floatx4;

__device__ inline unsigned short f2bf(float f) {
  unsigned int u = __builtin_bit_cast(unsigned int, f);
  u += 0x7fff + ((u >> 16) & 1);   // RNE
  return (unsigned short)(u >> 16);
}
__device__ inline float bf2f(unsigned short u) {
  unsigned int x = ((unsigned int)u) << 16;
  return __builtin_bit_cast(float, x);
}

// ---------- Kernel 0: W fp32 [C][H] -> WT bf16 [192][C] (transposed) ----------
__global__ __launch_bounds__(256) void wconv(
    const float* __restrict__ Wq, const float* __restrict__ Wk,
    const float* __restrict__ Wv, unsigned short* __restrict__ WT) {
  __shared__ __align__(16) float Ttile[32][68];
  int bid = blockIdx.x;
  int w = bid >> 5;             // which W
  int c0 = (bid & 31) * 32;     // c-range
  const float* __restrict__ W = (w == 0) ? Wq : (w == 1 ? Wk : Wv);
  int t = threadIdx.x;
  {
    int i = t >> 3, h0 = (t & 7) * 8;
    float4 a = *(const float4*)&W[(size_t)(c0 + i) * Hh + h0];
    float4 b = *(const float4*)&W[(size_t)(c0 + i) * Hh + h0 + 4];
    *(float4*)&Ttile[i][h0] = a;
    *(float4*)&Ttile[i][h0 + 4] = b;
  }
  __syncthreads();
  int h = t >> 2, jj = t & 3;
  unsigned short tmp[8];
#pragma unroll
  for (int ii = 0; ii < 8; ++ii) tmp[ii] = f2bf(Ttile[jj * 8 + ii][h]);
  unsigned short* dst = &WT[(size_t)(w * 64 + h) * Cc + c0 + jj * 8];
  *(ushort4*)dst = make_ushort4(tmp[0], tmp[1], tmp[2], tmp[3]);
  *(ushort4*)(dst + 4) = make_ushort4(tmp[4], tmp[5], tmp[6], tmp[7]);
}

// ---------- Kernel 1: fused QKV projection ----------
// grid 512 (M=32 rows each), 256 threads (4 waves). N=192, BK=32.
// LDS A/B in flat fragment-major layout: reader lane reads base+lane*16
// (conflict-free b128). Wave wv covers n16-groups wv*3..wv*3+2.
__global__ __launch_bounds__(256) void qkv3(
    const float* __restrict__ x, const unsigned short* __restrict__ WT,
    unsigned short* __restrict__ Qb, unsigned short* __restrict__ Kb,
    unsigned short* __restrict__ VTb) {
  __shared__ __align__(16) unsigned short As[2 * 512];    // 2 m-subs * 1KB
  __shared__ __align__(16) unsigned short Bs[12 * 512];   // 12 n16-groups * 1KB

  int mt = blockIdx.x;
  int t = threadIdx.x;
  int wv = t >> 6, lane = t & 63;
  int lrow = lane & 15, quad = lane >> 4;

  floatx4 acc[2][3];
#pragma unroll
  for (int m = 0; m < 2; ++m)
#pragma unroll
    for (int j = 0; j < 3; ++j)
#pragma unroll
      for (int r = 0; r < 4; ++r) acc[m][j][r] = 0.f;

  const float* xb = x + (size_t)mt * 32 * Cc;
  int arow = t >> 3, acg = t & 7;   // A-staging: row 0..31, k-group 0..7

  for (int kk = 0; kk < 32; ++kk) {
    int k0 = kk * 32;
    __syncthreads();
    // stage A: x fp32 -> bf16, frag-major. elem (m_row, k=acg*4..+3):
    // dst ushort idx = (row>>4)*512 + ((acg>>1)*16 + (row&15))*8 + (acg&1)*4
    {
      float4 v = *(const float4*)(xb + (size_t)arow * Cc + k0 + acg * 4);
      int di = (arow >> 4) * 512 + ((acg >> 1) * 16 + (arow & 15)) * 8 + (acg & 1) * 4;
      *(ushort4*)&As[di] = make_ushort4(f2bf(v.x), f2bf(v.y), f2bf(v.z), f2bf(v.w));
    }
    // stage B: WT bf16 copy, frag-major. task: kc = task&3, n = task>>2
#pragma unroll
    for (int i = 0; i < 3; ++i) {
      int task = t + i * 256;
      int kc = task & 3, n = task >> 2;
      int di = (n >> 4) * 512 + (kc * 16 + (n & 15)) * 8;
      *(uint4*)&Bs[di] = *(const uint4*)&WT[(size_t)n * Cc + k0 + kc * 8];
    }
    __syncthreads();
    short8 a0 = *(const short8*)&As[lane * 8];
    short8 a1 = *(const short8*)&As[512 + lane * 8];
#pragma unroll
    for (int j = 0; j < 3; ++j) {
      short8 b = *(const short8*)&Bs[(wv * 3 + j) * 512 + lane * 8];
      acc[0][j] = __builtin_amdgcn_mfma_f32_16x16x32_bf16(a0, b, acc[0][j], 0, 0, 0);
      acc[1][j] = __builtin_amdgcn_mfma_f32_16x16x32_bf16(a1, b, acc[1][j], 0, 0, 0);
    }
  }
  // epilogue: D row=quad*4+r (+msub*16), col=lrow (+n16*16)
#pragma unroll
  for (int m = 0; m < 2; ++m) {
#pragma unroll
    for (int j = 0; j < 3; ++j) {
      int nbase = (wv * 3 + j) * 16;
      int region = nbase >> 6;
      int row0 = mt * 32 + m * 16 + quad * 4;
      if (region == 2) {
        int h = nbase - 128 + lrow;
        *(ushort4*)&VTb[(size_t)h * BT + row0] =
            make_ushort4(f2bf(acc[m][j][0]), f2bf(acc[m][j][1]),
                         f2bf(acc[m][j][2]), f2bf(acc[m][j][3]));
      } else {
        unsigned short* dst = region ? Kb : Qb;
        int col = (nbase & 63) + lrow;
#pragma unroll
        for (int r = 0; r < 4; ++r)
          dst[(size_t)(row0 + r) * Hh + col] = f2bf(acc[m][j][r]);
      }
    }
  }
}

// ---------- Kernel 2: causal attention, no-max softmax, frag loads from global ----------
// grid 256 blocks (b, j), 512 threads (8 waves). Block handles query tiles
// j and 63-j sequentially; each tile's key blocks (64 keys) are split 8-way
// across waves (wave wv takes kt = wv, wv+8, ...). No barriers in K-loop.
// Unnormalized softmax: P = exp2(S*scale*log2e) (bounded: |S*scale| <~ 54),
// l via ones-column MFMA. Partials combined through LDS (bf16 O + fp32 l).
__global__ __launch_bounds__(512) void attn3(
    const unsigned short* __restrict__ Qb, const unsigned short* __restrict__ Kb,
    const unsigned short* __restrict__ VTb, float* __restrict__ out) {
  // [0,32K): per-wave P scratch (wv*4096 B) during compute; combine-O after.
  // [32K, 33K): l partials [8 waves][32 queries] fp32.
  __shared__ __align__(16) unsigned char smem[33 * 1024];
  unsigned short* Pall = (unsigned short*)smem;
  unsigned short* Ocomb = (unsigned short*)smem;
  float* Lcomb = (float*)(smem + 32768);

  int bid = blockIdx.x;
  int b = bid >> 5;
  int j = bid & 31;
  int t = threadIdx.x;
  int wv = t >> 6, lane = t & 63;
  int lrow = lane & 15, quad = lane >> 4;

  unsigned short* Pw = Pall + wv * 2048;   // this wave's 4KB P scratch

  short8 ones;
#pragma unroll
  for (int i = 0; i < 8; ++i) ones[i] = (short)0x3F80;   // bf16 1.0

  for (int half = 0; half < 2; ++half) {
    int qt = half ? (63 - j) : j;
    int q0 = qt * 32;
    int nkt = (qt >> 1) + 1;

    // Q A-frags: A[m=lrow][k=quad*8+jj], direct from global
    short8 aq[2][2];
#pragma unroll
    for (int qs = 0; qs < 2; ++qs)
#pragma unroll
      for (int kc = 0; kc < 2; ++kc)
        aq[qs][kc] = *(const short8*)
            &Qb[(size_t)(b * Tt + q0 + qs * 16 + lrow) * Hh + kc * 32 + quad * 8];

    floatx4 acc_o[2][4];
    floatx4 acc_l[2];
#pragma unroll
    for (int qs = 0; qs < 2; ++qs) {
#pragma unroll
      for (int r = 0; r < 4; ++r) acc_l[qs][r] = 0.f;
#pragma unroll
      for (int hs = 0; hs < 4; ++hs)
#pragma unroll
        for (int r = 0; r < 4; ++r) acc_o[qs][hs][r] = 0.f;
    }

    for (int kt = wv; kt < nkt; kt += 8) {
      int kbase = b * Tt + kt * 64;
      // K B-frags (S): lane(n=lrow key, quad k-chunk) reads 16B from Kb row
      short8 kf[4][2], vf[4][2];
#pragma unroll
      for (int sn = 0; sn < 4; ++sn)
#pragma unroll
        for (int kc = 0; kc < 2; ++kc)
          kf[sn][kc] = *(const short8*)
              &Kb[(size_t)(kbase + sn * 16 + lrow) * Hh + kc * 32 + quad * 8];
      // VT B-frags (PV): lane(n=lrow h, quad tok-chunk) reads 16B from VTb row
#pragma unroll
      for (int hs = 0; hs < 4; ++hs)
#pragma unroll
        for (int kc = 0; kc < 2; ++kc)
          vf[hs][kc] = *(const short8*)
              &VTb[(size_t)(hs * 16 + lrow) * BT + kbase + kc * 32 + quad * 8];

      // S = Q K^T (16 MFMAs)
      floatx4 s[2][4];
#pragma unroll
      for (int qs = 0; qs < 2; ++qs)
#pragma unroll
        for (int sn = 0; sn < 4; ++sn) {
          floatx4 z;
#pragma unroll
          for (int r = 0; r < 4; ++r) z[r] = 0.f;
          z = __builtin_amdgcn_mfma_f32_16x16x32_bf16(aq[qs][0], kf[sn][0], z, 0, 0, 0);
          z = __builtin_amdgcn_mfma_f32_16x16x32_bf16(aq[qs][1], kf[sn][1], z, 0, 0, 0);
          s[qs][sn] = z;
        }

      // mask (diagonal block only) + exp2 + write P to reader-linear LDS
      bool diag = (kt == nkt - 1);
#pragma unroll
      for (int qs = 0; qs < 2; ++qs)
#pragma unroll
        for (int sn = 0; sn < 4; ++sn) {
          int k5 = (sn & 1) * 16 + lrow;            // key within 32-chunk
          int slot = qs * 2 + (sn >> 1);            // A-frag slot
          int rlbase = (k5 >> 3) * 16;              // reader-lane base
#pragma unroll
          for (int r = 0; r < 4; ++r) {
            float v = s[qs][sn][r] * SLOG2E;
            if (diag) {
              int gk = kt * 64 + sn * 16 + lrow;
              int gq = q0 + qs * 16 + quad * 4 + r;
              if (gk > gq) v = -INFINITY;
            }
            float p = exp2f(v);
            Pw[slot * 512 + (rlbase + quad * 4 + r) * 8 + (k5 & 7)] = f2bf(p);
          }
        }

      // P A-frags: linear per-lane read (conflict-free)
      short8 ap[2][2];
#pragma unroll
      for (int qs = 0; qs < 2; ++qs)
#pragma unroll
        for (int kc = 0; kc < 2; ++kc)
          ap[qs][kc] = *(const short8*)&Pw[(qs * 2 + kc) * 512 + lane * 8];

      // l += P * ones ; O += P * V (20 MFMAs)
#pragma unroll
      for (int qs = 0; qs < 2; ++qs) {
        acc_l[qs] = __builtin_amdgcn_mfma_f32_16x16x32_bf16(ap[qs][0], ones, acc_l[qs], 0, 0, 0);
        acc_l[qs] = __builtin_amdgcn_mfma_f32_16x16x32_bf16(ap[qs][1], ones, acc_l[qs], 0, 0, 0);
#pragma unroll
        for (int hs = 0; hs < 4; ++hs) {
          acc_o[qs][hs] = __builtin_amdgcn_mfma_f32_16x16x32_bf16(ap[qs][0], vf[hs][0], acc_o[qs][hs], 0, 0, 0);
          acc_o[qs][hs] = __builtin_amdgcn_mfma_f32_16x16x32_bf16(ap[qs][1], vf[hs][1], acc_o[qs][hs], 0, 0, 0);
        }
      }
    }

    // ---- combine partials ----
    // O partial bf16: wave writes its own region (same bytes as its P scratch)
#pragma unroll
    for (int qs = 0; qs < 2; ++qs)
#pragma unroll
      for (int hs = 0; hs < 4; ++hs) {
        int s8 = qs * 4 + hs;
        *(ushort4*)&Ocomb[((wv * 8 + s8) * 64 + lane) * 4] =
            make_ushort4(f2bf(acc_o[qs][hs][0]), f2bf(acc_o[qs][hs][1]),
                         f2bf(acc_o[qs][hs][2]), f2bf(acc_o[qs][hs][3]));
      }
    if (lrow == 0) {
#pragma unroll
      for (int qs = 0; qs < 2; ++qs)
#pragma unroll
        for (int r = 0; r < 4; ++r)
          Lcomb[wv * 32 + qs * 16 + quad * 4 + r] = acc_l[qs][r];
    }
    __syncthreads();

    // reduce: thread (slot=wv, lane) sums 8 wave-partials and stores
    {
      int qsub = wv >> 2, hs = wv & 3;
      float o[4] = {0.f, 0.f, 0.f, 0.f};
#pragma unroll
      for (int w = 0; w < 8; ++w) {
        ushort4 pk = *(const ushort4*)&Ocomb[((w * 8 + wv) * 64 + lane) * 4];
        o[0] += bf2f(pk.x); o[1] += bf2f(pk.y);
        o[2] += bf2f(pk.z); o[3] += bf2f(pk.w);
      }
#pragma unroll
      for (int r = 0; r < 4; ++r) {
        float lv = 0.f;
#pragma unroll
        for (int w = 0; w < 8; ++w)
          lv += Lcomb[w * 32 + qsub * 16 + quad * 4 + r];
        int row = q0 + qsub * 16 + quad * 4 + r;
        out[(size_t)(b * Tt + row) * Hh + hs * 16 + lrow] = o[r] / lv;
      }
    }
    __syncthreads();   // before next half reuses P/O region
  }
}

extern "C" void kernel_launch(void* const* d_in, const int* in_sizes, int n_in,
                              void* d_out, int out_size, void* d_ws, size_t ws_size,
                              hipStream_t stream) {
  const float* x = (const float*)d_in[0];
  const float* Wq = (const float*)d_in[1];
  const float* Wk = (const float*)d_in[2];
  const float* Wv = (const float*)d_in[3];
  float* out = (float*)d_out;

  unsigned short* WT = (unsigned short*)d_ws;          // [192][1024]
  unsigned short* Qb = WT + 192 * 1024;                // [BT][64]
  unsigned short* Kb = Qb + (size_t)BT * Hh;           // [BT][64]
  unsigned short* VTb = Kb + (size_t)BT * Hh;          // [64][BT]

  wconv<<<dim3(96), dim3(256), 0, stream>>>(Wq, Wk, Wv, WT);
  qkv3<<<dim3(512), dim3(256), 0, stream>>>(x, WT, Qb, Kb, VTb);
  attn3<<<dim3(256), dim3(512), 0, stream>>>(Qb, Kb, VTb, out);
}